// Round 13
// baseline (800.062 us; speedup 1.0000x reference)
//
#include <hip/hip_runtime.h>
#include <hip/hip_bf16.h>

#define B_ 64
#define N_ 4096
#define C_ 256
#define K_ 8
#define M_ (B_*N_)
#define ITERS_ 3
#define SCALE_ 0.0625f
#define EPS_ 1e-8f

typedef __attribute__((ext_vector_type(4))) float f32x4;
typedef __attribute__((ext_vector_type(8))) __bf16 bf16x8;
typedef __attribute__((ext_vector_type(8))) unsigned short ushort8;
typedef __attribute__((ext_vector_type(4))) unsigned short ushort4v;

static __device__ __forceinline__ unsigned short f2bf(float f){
    union { float f; unsigned u; } v; v.f = f;
    unsigned r = v.u + 0x7fffu + ((v.u >> 16) & 1u);
    return (unsigned short)(r >> 16);
}
static __device__ __forceinline__ float bf2f(unsigned short h){
    union { unsigned u; float f; } v; v.u = ((unsigned)h) << 16;
    return v.f;
}

// ---------------- prep: slots init + WkT transpose ----------------
__global__ void prep_kernel(const float* __restrict__ mu, const float* __restrict__ lsig,
                            const float* __restrict__ noise, const float* __restrict__ Wk,
                            float* __restrict__ slots, float* __restrict__ WkT){
    int idx = blockIdx.x*256 + threadIdx.x;   // grid 512 -> 0..131071
    int c = idx & 255, i = (idx >> 8) & 7;
    slots[idx] = mu[c] + expf(lsig[c])*noise[i*256 + c];
    if (idx < 65536){
        int cc = idx >> 8, d = idx & 255;     // WkT[cc][d] = Wk[d][cc]
        WkT[idx] = Wk[(size_t)d*256 + cc];
    }
}

// ---------------- x -> x_hat bf16; layout XH[jt][og(0..7)][rloc(0..255)][32c] ----------------
__global__ void ln_kernel(const float* __restrict__ x, const float* __restrict__ g,
                          const float* __restrict__ bta, unsigned short* __restrict__ XH){
    const int t = threadIdx.x;
    const int row = blockIdx.x*32 + (t >> 3), s = t & 7;
    const float* xr = x + (size_t)row*C_;
    float v[32];
    #pragma unroll
    for (int q = 0; q < 8; ++q)
        *(float4*)&v[q*4] = *(const float4*)(xr + s*4 + q*32);
    float sum = 0.f, sq = 0.f;
    #pragma unroll
    for (int e = 0; e < 32; ++e){ sum += v[e]; sq += v[e]*v[e]; }
    #pragma unroll
    for (int m = 1; m < 8; m <<= 1){ sum += __shfl_xor(sum, m); sq += __shfl_xor(sq, m); }
    float mean = sum * (1.f/256.f);
    float rstd = rsqrtf(sq * (1.f/256.f) - mean*mean + 1e-5f);
    const int jt = row >> 8, rloc = row & 255;
    #pragma unroll
    for (int q = 0; q < 8; ++q){
        float4 g4 = *(const float4*)(g + q*32 + s*4);
        float4 b4 = *(const float4*)(bta + q*32 + s*4);
        ushort4v pk;
        pk[0] = f2bf((v[q*4+0] - mean)*rstd*g4.x + b4.x);
        pk[1] = f2bf((v[q*4+1] - mean)*rstd*g4.y + b4.y);
        pk[2] = f2bf((v[q*4+2] - mean)*rstd*g4.z + b4.z);
        pk[3] = f2bf((v[q*4+3] - mean)*rstd*g4.w + b4.w);
        *(ushort4v*)(XH + (((size_t)jt*8 + q)*256 + rloc)*32 + s*4) = pk;
    }
}

// ---------------- fused attn (unchanged from R11/R12-validated math) ----------------
__global__ __launch_bounds__(512)
void attn_kernel(const unsigned short* __restrict__ XH, const float* __restrict__ qt,
                 const float* __restrict__ qb, float* __restrict__ Spart,
                 float* __restrict__ Upart){
    __shared__ __align__(16) unsigned short xs[2*16384];
    __shared__ __align__(16) unsigned short pst[16*72];
    __shared__ float swred[4][8];
    const int t = threadIdx.x, b = blockIdx.x, jb = blockIdx.y;
    const unsigned short* XB = XH + (size_t)(b*16 + jb)*65536;
    const int wv = t >> 6, l = t & 63;
    const int bi = l & 15, kg = l >> 4;
    const bool isQK = (wv < 4), isPV = (wv >= 4);

    bf16x8 bfrag[8];
    float qbl = 0.f;
    {
        const ushort8 zz = (ushort8){0,0,0,0,0,0,0,0};
        #pragma unroll
        for (int ks = 0; ks < 8; ++ks) bfrag[ks] = __builtin_bit_cast(bf16x8, zz);
        if (isQK && bi < 8){
            #pragma unroll
            for (int ks = 0; ks < 8; ++ks){
                const float* qp = qt + ((size_t)b*8 + bi)*256 + ks*32 + kg*8;
                float4 qa = *(const float4*)qp;
                float4 qc = *(const float4*)(qp + 4);
                ushort8 pk;
                pk[0]=f2bf(qa.x); pk[1]=f2bf(qa.y); pk[2]=f2bf(qa.z); pk[3]=f2bf(qa.w);
                pk[4]=f2bf(qc.x); pk[5]=f2bf(qc.y); pk[6]=f2bf(qc.z); pk[7]=f2bf(qc.w);
                bfrag[ks] = __builtin_bit_cast(bf16x8, pk);
            }
            qbl = qb[(size_t)b*8 + bi];
        }
    }
    ushort8 SbA[4], SbB[4];
    const int strow[4] = { (l >> 2), 16 + (l >> 2), 32 + (l >> 2), 48 + (l >> 2) };
    f32x4 acc[4];
    #pragma unroll
    for (int n = 0; n < 4; ++n) acc[n] = (f32x4){0.f,0.f,0.f,0.f};
    const int pv_lo = bi & 7;
    const int pv_sl = (bi >> 3) ^ (kg << 1);
    float s8loc = 0.f;

#define STG_LOAD(Sb, ch) { \
    const unsigned short* gp = XB + (size_t)wv*8192 + (ch)*2048 + l*8; \
    _Pragma("unroll") for (int u = 0; u < 4; ++u) Sb[u] = *(const ushort8*)(gp + u*512); }
#define STG_WRITE(Sb, ch) { \
    unsigned short* xw = &xs[((ch)&1)*16384]; \
    _Pragma("unroll") for (int u = 0; u < 4; ++u){ \
        int rr = strow[u]; \
        int o = (wv*4 + (l & 3)) ^ ((rr & 7) ^ (((rr >> 3) & 3) << 1)); \
        *(ushort8*)&xw[rr*256 + o*8] = Sb[u]; } }
#define BARR() { asm volatile("s_waitcnt lgkmcnt(0)" ::: "memory"); __builtin_amdgcn_s_barrier(); }

#define QK_PHASE(p) if (isQK){ \
    const int cur = ((p)&1)*16384; \
    f32x4 qacc = (f32x4){0.f,0.f,0.f,0.f}; \
    const int rowL = wv*16 + bi; \
    const int swrow = (rowL & 7) ^ (((rowL >> 3) & 3) << 1); \
    const unsigned short* xrow = &xs[cur + rowL*256]; \
    _Pragma("unroll") for (int ks = 0; ks < 8; ++ks){ \
        int chn = (ks*4 + kg) ^ swrow; \
        bf16x8 af = *(const bf16x8*)&xrow[chn*8]; \
        qacc = __builtin_amdgcn_mfma_f32_16x16x32_bf16(af, bfrag[ks], qacc, 0, 0, 0); } \
    ushort4v p4; \
    _Pragma("unroll") for (int rr = 0; rr < 4; ++rr){ \
        float d = qacc[rr] + qbl; \
        float mx = d; \
        mx = fmaxf(mx, __shfl_xor(mx, 1)); \
        mx = fmaxf(mx, __shfl_xor(mx, 2)); \
        mx = fmaxf(mx, __shfl_xor(mx, 4)); \
        float e = __expf(d - mx); \
        float se = e; \
        se += __shfl_xor(se, 1); \
        se += __shfl_xor(se, 2); \
        se += __shfl_xor(se, 4); \
        float pv = e/se + EPS_; \
        p4[rr] = f2bf(pv); \
        if (bi < 8) s8loc += pv; } \
    if (bi < 8) *(ushort4v*)&pst[bi*72 + wv*16 + kg*4] = p4; }

#define PV_PHASE(p) if (isPV){ \
    const int cur = ((p)&1)*16384; \
    _Pragma("unroll") for (int kh = 0; kh < 2; ++kh){ \
        ushort8 pa = *(const ushort8*)&pst[bi*72 + kh*32 + kg*8]; \
        _Pragma("unroll") for (int n = 0; n < 4; ++n){ \
            const int ct2 = ((wv - 4)*4 + n) << 1; \
            ushort8 xv; \
            _Pragma("unroll") for (int e = 0; e < 8; ++e){ \
                int slot = ct2 ^ pv_sl ^ e; \
                xv[e] = xs[cur + kh*8192 + kg*2048 + e*256 + (slot << 3) + pv_lo]; } \
            acc[n] = __builtin_amdgcn_mfma_f32_16x16x32_bf16( \
                __builtin_bit_cast(bf16x8, pa), __builtin_bit_cast(bf16x8, xv), acc[n], 0, 0, 0); } } }

    STG_LOAD(SbA, 0); STG_WRITE(SbA, 0);
    STG_LOAD(SbB, 1);
    BARR();

    STG_LOAD(SbA, 2);
    QK_PHASE(0)
    BARR();
    PV_PHASE(0)
    STG_WRITE(SbB, 1);
    BARR();
    STG_LOAD(SbB, 3);
    QK_PHASE(1)
    BARR();
    PV_PHASE(1)
    STG_WRITE(SbA, 2);
    BARR();
    QK_PHASE(2)
    BARR();
    PV_PHASE(2)
    STG_WRITE(SbB, 3);
    BARR();
    QK_PHASE(3)
    BARR();
    PV_PHASE(3)

    if (isQK){
        float s = s8loc;
        s += __shfl_xor(s, 16);
        s += __shfl_xor(s, 32);
        if (l < 8) swred[wv][l] = s;
    }
    BARR();
    if (t < 8)
        Spart[((size_t)(b*16 + jb))*8 + t] =
            swred[0][t] + swred[1][t] + swred[2][t] + swred[3][t];
    if (isPV && kg < 2){
        #pragma unroll
        for (int n = 0; n < 4; ++n){
            const int ct = (wv - 4)*4 + n;
            #pragma unroll
            for (int r2 = 0; r2 < 4; ++r2){
                int i = kg*4 + r2;
                Upart[(((size_t)(b*16 + jb))*8 + i)*256 + ct*16 + bi] = acc[n][r2];
            }
        }
    }
#undef STG_LOAD
#undef STG_WRITE
#undef BARR
#undef QK_PHASE
#undef PV_PHASE
}

// ---------------- slotU: full slot-side update + next-iter q~ (grid 64, 512 thr; slot = wave) ----------------
// first=1: skip update phases; just LN_s(slots) -> q~, qb.
__global__ void slotU_kernel(int first, const float* __restrict__ Spart, const float* __restrict__ Upart,
                             const float* __restrict__ Wv, const float* __restrict__ bv,
                             const float* __restrict__ W_ih, const float* __restrict__ b_ih,
                             const float* __restrict__ W_hh, const float* __restrict__ b_hh,
                             const float* __restrict__ gf, const float* __restrict__ bf,
                             const float* __restrict__ W1, const float* __restrict__ b1,
                             const float* __restrict__ W2, const float* __restrict__ b2,
                             const float* __restrict__ gs, const float* __restrict__ bs,
                             const float* __restrict__ Wq, const float* __restrict__ bq,
                             const float* __restrict__ WkT, const float* __restrict__ bk,
                             float* __restrict__ slots, float* __restrict__ qtbuf,
                             float* __restrict__ qbb, float* __restrict__ dout){
    __shared__ float us[8][260], sp[8][260], upd[8][260], s2[8][260];
    __shared__ float pre[8][260], hb[8][260], sn[8][260], qv[8][260];
    const int t = threadIdx.x, b = blockIdx.x;
    const int i = t >> 6, l = t & 63, c0 = l*4;

    if (!first){
        // A: reduce Upart/Spart + load prev slots
        {
            float a0=0.f, a1=0.f, a2=0.f, a3=0.f, S=0.f;
            #pragma unroll
            for (int jb = 0; jb < 16; ++jb){
                float4 u4 = *(const float4*)(Upart + (((size_t)(b*16 + jb))*8 + i)*256 + c0);
                a0 += u4.x; a1 += u4.y; a2 += u4.z; a3 += u4.w;
                S += Spart[((size_t)(b*16 + jb))*8 + i];
            }
            float invS = 1.f / S;
            us[i][c0+0] = a0*invS; us[i][c0+1] = a1*invS;
            us[i][c0+2] = a2*invS; us[i][c0+3] = a3*invS;
            float4 s4 = *(const float4*)(slots + ((size_t)b*8 + i)*256 + c0);
            sp[i][c0+0] = s4.x; sp[i][c0+1] = s4.y; sp[i][c0+2] = s4.z; sp[i][c0+3] = s4.w;
        }
        __syncthreads();
        // B: upd = us @ Wv + bv
        {
            float4 acc = *(const float4*)(bv + c0);
            #pragma unroll 2
            for (int cb = 0; cb < 256; cb += 16){
                float4 w4[16];
                #pragma unroll
                for (int u = 0; u < 16; ++u)
                    w4[u] = *(const float4*)(Wv + (size_t)(cb+u)*256 + c0);
                #pragma unroll
                for (int u = 0; u < 16; ++u){
                    float uv = us[i][cb+u];
                    acc.x += uv*w4[u].x; acc.y += uv*w4[u].y;
                    acc.z += uv*w4[u].z; acc.w += uv*w4[u].w;
                }
            }
            *(float4*)&upd[i][c0] = acc;
        }
        __syncthreads();
        // C: GRU (4 cols/thread, 6 float4 streams chunk 4)
        {
            float4 xr = *(const float4*)(b_ih + c0);
            float4 xz = *(const float4*)(b_ih + 256 + c0);
            float4 xn = *(const float4*)(b_ih + 512 + c0);
            float4 hr = *(const float4*)(b_hh + c0);
            float4 hz = *(const float4*)(b_hh + 256 + c0);
            float4 hn = *(const float4*)(b_hh + 512 + c0);
            for (int cb = 0; cb < 256; cb += 4){
                float4 wi0[4], wi1[4], wi2[4], wh0[4], wh1[4], wh2[4];
                #pragma unroll
                for (int u = 0; u < 4; ++u){
                    const float* wi = W_ih + (size_t)(cb+u)*768 + c0;
                    const float* wh = W_hh + (size_t)(cb+u)*768 + c0;
                    wi0[u] = *(const float4*)(wi);
                    wi1[u] = *(const float4*)(wi + 256);
                    wi2[u] = *(const float4*)(wi + 512);
                    wh0[u] = *(const float4*)(wh);
                    wh1[u] = *(const float4*)(wh + 256);
                    wh2[u] = *(const float4*)(wh + 512);
                }
                #pragma unroll
                for (int u = 0; u < 4; ++u){
                    float uv = upd[i][cb+u], sv = sp[i][cb+u];
                    xr.x += uv*wi0[u].x; xr.y += uv*wi0[u].y; xr.z += uv*wi0[u].z; xr.w += uv*wi0[u].w;
                    xz.x += uv*wi1[u].x; xz.y += uv*wi1[u].y; xz.z += uv*wi1[u].z; xz.w += uv*wi1[u].w;
                    xn.x += uv*wi2[u].x; xn.y += uv*wi2[u].y; xn.z += uv*wi2[u].z; xn.w += uv*wi2[u].w;
                    hr.x += sv*wh0[u].x; hr.y += sv*wh0[u].y; hr.z += sv*wh0[u].z; hr.w += sv*wh0[u].w;
                    hz.x += sv*wh1[u].x; hz.y += sv*wh1[u].y; hz.z += sv*wh1[u].z; hz.w += sv*wh1[u].w;
                    hn.x += sv*wh2[u].x; hn.y += sv*wh2[u].y; hn.z += sv*wh2[u].z; hn.w += sv*wh2[u].w;
                }
            }
            #pragma unroll
            for (int e = 0; e < 4; ++e){
                float xre = ((const float*)&xr)[e], xze = ((const float*)&xz)[e], xne = ((const float*)&xn)[e];
                float hre = ((const float*)&hr)[e], hze = ((const float*)&hz)[e], hne = ((const float*)&hn)[e];
                float rv = 1.f/(1.f + __expf(-(xre + hre)));
                float zv = 1.f/(1.f + __expf(-(xze + hze)));
                float nn = tanhf(xne + rv*hne);
                s2[i][c0+e] = (1.f - zv)*nn + zv*sp[i][c0+e];
            }
        }
        __syncthreads();
        // D: LN_ff (slot = wave, pure wave reduce)
        {
            float v0 = s2[i][c0+0], v1 = s2[i][c0+1], v2 = s2[i][c0+2], v3 = s2[i][c0+3];
            float sum = v0+v1+v2+v3;
            float sq  = v0*v0+v1*v1+v2*v2+v3*v3;
            #pragma unroll
            for (int m = 1; m < 64; m <<= 1){ sum += __shfl_xor(sum, m); sq += __shfl_xor(sq, m); }
            float mean = sum * (1.f/256.f);
            float rstd = rsqrtf(sq * (1.f/256.f) - mean*mean + 1e-5f);
            float4 g4 = *(const float4*)(gf + c0);
            float4 b4 = *(const float4*)(bf + c0);
            pre[i][c0+0] = (v0 - mean)*rstd*g4.x + b4.x;
            pre[i][c0+1] = (v1 - mean)*rstd*g4.y + b4.y;
            pre[i][c0+2] = (v2 - mean)*rstd*g4.z + b4.z;
            pre[i][c0+3] = (v3 - mean)*rstd*g4.w + b4.w;
        }
        __syncthreads();
        // E: FFN1
        {
            float4 acc = *(const float4*)(b1 + c0);
            #pragma unroll 2
            for (int cb = 0; cb < 256; cb += 16){
                float4 w4[16];
                #pragma unroll
                for (int u = 0; u < 16; ++u)
                    w4[u] = *(const float4*)(W1 + (size_t)(cb+u)*256 + c0);
                #pragma unroll
                for (int u = 0; u < 16; ++u){
                    float pv = pre[i][cb+u];
                    acc.x += pv*w4[u].x; acc.y += pv*w4[u].y;
                    acc.z += pv*w4[u].z; acc.w += pv*w4[u].w;
                }
            }
            hb[i][c0+0] = fmaxf(acc.x, 0.f); hb[i][c0+1] = fmaxf(acc.y, 0.f);
            hb[i][c0+2] = fmaxf(acc.z, 0.f); hb[i][c0+3] = fmaxf(acc.w, 0.f);
        }
        __syncthreads();
        // F: FFN2 + residual -> final; write global slots + dout; keep in sp for LN_s
        {
            float4 acc = *(const float4*)(b2 + c0);
            #pragma unroll 2
            for (int mb = 0; mb < 256; mb += 16){
                float4 w4[16];
                #pragma unroll
                for (int u = 0; u < 16; ++u)
                    w4[u] = *(const float4*)(W2 + (size_t)(mb+u)*256 + c0);
                #pragma unroll
                for (int u = 0; u < 16; ++u){
                    float hv = hb[i][mb+u];
                    acc.x += hv*w4[u].x; acc.y += hv*w4[u].y;
                    acc.z += hv*w4[u].z; acc.w += hv*w4[u].w;
                }
            }
            float4 fin;
            fin.x = s2[i][c0+0] + acc.x; fin.y = s2[i][c0+1] + acc.y;
            fin.z = s2[i][c0+2] + acc.z; fin.w = s2[i][c0+3] + acc.w;
            size_t off = ((size_t)b*8 + i)*256 + c0;
            *(float4*)(slots + off) = fin;
            *(float4*)(dout + off)  = fin;
            sp[i][c0+0] = fin.x; sp[i][c0+1] = fin.y; sp[i][c0+2] = fin.z; sp[i][c0+3] = fin.w;
        }
        __syncthreads();
    } else {
        float4 s4 = *(const float4*)(slots + ((size_t)b*8 + i)*256 + c0);
        sp[i][c0+0] = s4.x; sp[i][c0+1] = s4.y; sp[i][c0+2] = s4.z; sp[i][c0+3] = s4.w;
        __syncthreads();
    }

    // LN_s on sp -> sn
    {
        float v0 = sp[i][c0+0], v1 = sp[i][c0+1], v2 = sp[i][c0+2], v3 = sp[i][c0+3];
        float sum = v0+v1+v2+v3;
        float sq  = v0*v0+v1*v1+v2*v2+v3*v3;
        #pragma unroll
        for (int m = 1; m < 64; m <<= 1){ sum += __shfl_xor(sum, m); sq += __shfl_xor(sq, m); }
        float mean = sum * (1.f/256.f);
        float rstd = rsqrtf(sq * (1.f/256.f) - mean*mean + 1e-5f);
        float4 g4 = *(const float4*)(gs + c0);
        float4 b4 = *(const float4*)(bs + c0);
        sn[i][c0+0] = (v0 - mean)*rstd*g4.x + b4.x;
        sn[i][c0+1] = (v1 - mean)*rstd*g4.y + b4.y;
        sn[i][c0+2] = (v2 - mean)*rstd*g4.z + b4.z;
        sn[i][c0+3] = (v3 - mean)*rstd*g4.w + b4.w;
    }
    __syncthreads();
    // qv = sn @ Wq + bq
    {
        float4 acc = *(const float4*)(bq + c0);
        #pragma unroll 2
        for (int cb = 0; cb < 256; cb += 16){
            float4 w4[16];
            #pragma unroll
            for (int u = 0; u < 16; ++u)
                w4[u] = *(const float4*)(Wq + (size_t)(cb+u)*256 + c0);
            #pragma unroll
            for (int u = 0; u < 16; ++u){
                float sv = sn[i][cb+u];
                acc.x += sv*w4[u].x; acc.y += sv*w4[u].y;
                acc.z += sv*w4[u].z; acc.w += sv*w4[u].w;
            }
        }
        qv[i][c0+0] = acc.x; qv[i][c0+1] = acc.y;
        qv[i][c0+2] = acc.z; qv[i][c0+3] = acc.w;
    }
    __syncthreads();
    // qt = SCALE * qv @ WkT ; qb = SCALE * qv . bk
    {
        float4 acc = (float4){0.f,0.f,0.f,0.f};
        #pragma unroll 2
        for (int cb = 0; cb < 256; cb += 16){
            float4 w4[16];
            #pragma unroll
            for (int u = 0; u < 16; ++u)
                w4[u] = *(const float4*)(WkT + (size_t)(cb+u)*256 + c0);
            #pragma unroll
            for (int u = 0; u < 16; ++u){
                float qvv = qv[i][cb+u];
                acc.x += qvv*w4[u].x; acc.y += qvv*w4[u].y;
                acc.z += qvv*w4[u].z; acc.w += qvv*w4[u].w;
            }
        }
        float4 o;
        o.x = SCALE_*acc.x; o.y = SCALE_*acc.y; o.z = SCALE_*acc.z; o.w = SCALE_*acc.w;
        *(float4*)(qtbuf + ((size_t)b*8 + i)*256 + c0) = o;
        float4 k4 = *(const float4*)(bk + c0);
        float pb = qv[i][c0+0]*k4.x + qv[i][c0+1]*k4.y + qv[i][c0+2]*k4.z + qv[i][c0+3]*k4.w;
        #pragma unroll
        for (int m = 1; m < 64; m <<= 1) pb += __shfl_xor(pb, m);
        if (l == 0) qbb[(size_t)b*8 + i] = SCALE_*pb;
    }
}

extern "C" void kernel_launch(void* const* d_in, const int* in_sizes, int n_in,
                              void* d_out, int out_size, void* d_ws, size_t ws_size,
                              hipStream_t stream){
    const float* inputs = (const float*)d_in[0];
    const float* noise  = (const float*)d_in[1];
    const float* mu     = (const float*)d_in[2];
    const float* lsig   = (const float*)d_in[3];
    const float* g_in   = (const float*)d_in[4];
    const float* b_in   = (const float*)d_in[5];
    const float* g_s    = (const float*)d_in[6];
    const float* b_s    = (const float*)d_in[7];
    const float* g_ff   = (const float*)d_in[8];
    const float* b_ff   = (const float*)d_in[9];
    const float* Wq     = (const float*)d_in[10];
    const float* bq     = (const float*)d_in[11];
    const float* Wk     = (const float*)d_in[12];
    const float* bk     = (const float*)d_in[13];
    const float* Wv     = (const float*)d_in[14];
    const float* bv     = (const float*)d_in[15];
    const float* W_ih   = (const float*)d_in[16];
    const float* b_ih   = (const float*)d_in[17];
    const float* W_hh   = (const float*)d_in[18];
    const float* b_hh   = (const float*)d_in[19];
    const float* W1     = (const float*)d_in[20];
    const float* b1     = (const float*)d_in[21];
    const float* W2     = (const float*)d_in[22];
    const float* b2     = (const float*)d_in[23];

    char* ws = (char*)d_ws;
    unsigned short* XH  = (unsigned short*)(ws);               // 128 MB
    float* Upart        = (float*)(ws + ((size_t)128 << 20));  // 8 MB
    float* Spart        = (float*)(ws + ((size_t)136 << 20));  // 8 KB
    float* qtbuf        = (float*)(ws + ((size_t)137 << 20));  // 512 KB
    float* qbb          = (float*)(ws + ((size_t)138 << 20));  // 2 KB
    float* slots        = (float*)(ws + ((size_t)139 << 20));  // 512 KB
    float* WkT          = (float*)(ws + ((size_t)140 << 20));  // 256 KB

    prep_kernel<<<512, 256, 0, stream>>>(mu, lsig, noise, Wk, slots, WkT);
    slotU_kernel<<<B_, 512, 0, stream>>>(1, Spart, Upart, Wv, bv, W_ih, b_ih, W_hh, b_hh,
                                         g_ff, b_ff, W1, b1, W2, b2, g_s, b_s, Wq, bq,
                                         WkT, bk, slots, qtbuf, qbb, (float*)d_out);
    ln_kernel<<<M_/32, 256, 0, stream>>>(inputs, g_in, b_in, XH);
    for (int it = 0; it < ITERS_; ++it){
        attn_kernel<<<dim3(B_, 16), 512, 0, stream>>>(XH, qtbuf, qbb, Spart, Upart);
        slotU_kernel<<<B_, 512, 0, stream>>>(0, Spart, Upart, Wv, bv, W_ih, b_ih, W_hh, b_hh,
                                             g_ff, b_ff, W1, b1, W2, b2, g_s, b_s, Wq, bq,
                                             WkT, bk, slots, qtbuf, qbb, (float*)d_out);
    }
}

// Round 14
// 466.701 us; speedup vs baseline: 1.7143x; 1.7143x over previous
//
#include <hip/hip_runtime.h>
#include <hip/hip_bf16.h>

#define B_ 64
#define N_ 4096
#define C_ 256
#define K_ 8
#define M_ (B_*N_)
#define ITERS_ 3
#define SCALE_ 0.0625f
#define EPS_ 1e-8f

typedef __attribute__((ext_vector_type(4))) float f32x4;
typedef __attribute__((ext_vector_type(8))) __bf16 bf16x8;
typedef __attribute__((ext_vector_type(8))) unsigned short ushort8;
typedef __attribute__((ext_vector_type(4))) unsigned short ushort4v;

static __device__ __forceinline__ unsigned short f2bf(float f){
    union { float f; unsigned u; } v; v.f = f;
    unsigned r = v.u + 0x7fffu + ((v.u >> 16) & 1u);
    return (unsigned short)(r >> 16);
}
static __device__ __forceinline__ float bf2f(unsigned short h){
    union { unsigned u; float f; } v; v.u = ((unsigned)h) << 16;
    return v.f;
}

// ---------------- prep1: slots init ----------------
__global__ void prep1_kernel(const float* __restrict__ mu, const float* __restrict__ lsig,
                             const float* __restrict__ noise, float* __restrict__ slots){
    int idx = blockIdx.x*256 + threadIdx.x;   // 0..131071
    int c = idx & 255, i = (idx >> 8) & 7;
    slots[idx] = mu[c] + expf(lsig[c])*noise[i*256 + c];
}

// ---------------- prep2: WqkT = Wq@Wk^T, bqt = bq@Wk^T, wqb = Wq@bk, bqk = bq.bk ----------------
__global__ void prep2_kernel(const float* __restrict__ Wq, const float* __restrict__ Wk,
                             const float* __restrict__ bq, const float* __restrict__ bk,
                             float* __restrict__ WqkT, float* __restrict__ bqt,
                             float* __restrict__ wqb, float* __restrict__ bqkv){
    __shared__ float wqrow[256], bkl[256], bql[256];
    __shared__ float red[4], red2[4];
    const int t = threadIdx.x, c = blockIdx.x;
    wqrow[t] = Wq[(size_t)c*256 + t];
    bkl[t] = bk[t];
    bql[t] = bq[t];
    __syncthreads();
    float acc = 0.f, accb = 0.f;
    const float* wkr = Wk + (size_t)t*256;
    #pragma unroll 4
    for (int d = 0; d < 256; d += 4){
        float4 wk4 = *(const float4*)(wkr + d);
        float4 wq4 = *(const float4*)(&wqrow[d]);
        float4 bq4 = *(const float4*)(&bql[d]);
        acc  += wq4.x*wk4.x + wq4.y*wk4.y + wq4.z*wk4.z + wq4.w*wk4.w;
        accb += bq4.x*wk4.x + bq4.y*wk4.y + bq4.z*wk4.z + bq4.w*wk4.w;
    }
    WqkT[(size_t)c*256 + t] = acc;
    if (c == 0) bqt[t] = accb;
    float pw = wqrow[t]*bkl[t];
    float pb = bql[t]*bkl[t];
    #pragma unroll
    for (int m = 1; m < 64; m <<= 1){ pw += __shfl_xor(pw, m); pb += __shfl_xor(pb, m); }
    if ((t & 63) == 0){ red[t >> 6] = pw; red2[t >> 6] = pb; }
    __syncthreads();
    if (t == 0){
        wqb[c] = red[0] + red[1] + red[2] + red[3];
        if (c == 0) bqkv[0] = red2[0] + red2[1] + red2[2] + red2[3];
    }
}

// ---------------- x -> x_hat bf16; layout XH[jt][og(0..7)][rloc(0..255)][32c] ----------------
__global__ void ln_kernel(const float* __restrict__ x, const float* __restrict__ g,
                          const float* __restrict__ bta, unsigned short* __restrict__ XH){
    const int t = threadIdx.x;
    const int row = blockIdx.x*32 + (t >> 3), s = t & 7;
    const float* xr = x + (size_t)row*C_;
    float v[32];
    #pragma unroll
    for (int q = 0; q < 8; ++q)
        *(float4*)&v[q*4] = *(const float4*)(xr + s*4 + q*32);
    float sum = 0.f, sq = 0.f;
    #pragma unroll
    for (int e = 0; e < 32; ++e){ sum += v[e]; sq += v[e]*v[e]; }
    #pragma unroll
    for (int m = 1; m < 8; m <<= 1){ sum += __shfl_xor(sum, m); sq += __shfl_xor(sq, m); }
    float mean = sum * (1.f/256.f);
    float rstd = rsqrtf(sq * (1.f/256.f) - mean*mean + 1e-5f);
    const int jt = row >> 8, rloc = row & 255;
    #pragma unroll
    for (int q = 0; q < 8; ++q){
        float4 g4 = *(const float4*)(g + q*32 + s*4);
        float4 b4 = *(const float4*)(bta + q*32 + s*4);
        ushort4v pk;
        pk[0] = f2bf((v[q*4+0] - mean)*rstd*g4.x + b4.x);
        pk[1] = f2bf((v[q*4+1] - mean)*rstd*g4.y + b4.y);
        pk[2] = f2bf((v[q*4+2] - mean)*rstd*g4.z + b4.z);
        pk[3] = f2bf((v[q*4+3] - mean)*rstd*g4.w + b4.w);
        *(ushort4v*)(XH + (((size_t)jt*8 + q)*256 + rloc)*32 + s*4) = pk;
    }
}

// ---------------- per-iter: slotq = LN_s + q~ = SCALE*(sn@Wqk + bqt), qb  (grid (B,4), 512) ----------------
__global__ __launch_bounds__(512, 1)
void slotq_kernel(const float* __restrict__ slots, const float* __restrict__ WqkT,
                  const float* __restrict__ bqt, const float* __restrict__ wqb,
                  const float* __restrict__ bqkv, const float* __restrict__ gs,
                  const float* __restrict__ bs, float* __restrict__ qtbuf,
                  float* __restrict__ qbb){
    __shared__ float sn[8][260];
    const int t = threadIdx.x, b = blockIdx.x, cgb = blockIdx.y;
    const int i = t >> 6, l = t & 63;
    {
        float4 v4 = *(const float4*)(slots + ((size_t)b*8 + i)*256 + l*4);
        float sum = v4.x + v4.y + v4.z + v4.w;
        float sq  = v4.x*v4.x + v4.y*v4.y + v4.z*v4.z + v4.w*v4.w;
        #pragma unroll
        for (int m = 1; m < 64; m <<= 1){ sum += __shfl_xor(sum, m); sq += __shfl_xor(sq, m); }
        float mean = sum * (1.f/256.f);
        float rstd = rsqrtf(sq * (1.f/256.f) - mean*mean + 1e-5f);
        float4 g4 = *(const float4*)(gs + l*4);
        float4 b4 = *(const float4*)(bs + l*4);
        float n0 = (v4.x - mean)*rstd*g4.x + b4.x;
        float n1 = (v4.y - mean)*rstd*g4.y + b4.y;
        float n2 = (v4.z - mean)*rstd*g4.z + b4.z;
        float n3 = (v4.w - mean)*rstd*g4.w + b4.w;
        sn[i][l*4+0] = n0; sn[i][l*4+1] = n1; sn[i][l*4+2] = n2; sn[i][l*4+3] = n3;
        if (cgb == 0){
            float4 w4 = *(const float4*)(wqb + l*4);
            float pb = n0*w4.x + n1*w4.y + n2*w4.z + n3*w4.w;
            #pragma unroll
            for (int m = 1; m < 64; m <<= 1) pb += __shfl_xor(pb, m);
            if (l == 0) qbb[(size_t)b*8 + i] = SCALE_*(pb + bqkv[0]);
        }
    }
    __syncthreads();
    const int col = cgb*64 + l;
    float acc = bqt[col];
    #pragma unroll
    for (int cb = 0; cb < 256; cb += 64){
        float w[64];
        #pragma unroll
        for (int u = 0; u < 64; ++u) w[u] = WqkT[(size_t)(cb+u)*256 + col];
        #pragma unroll
        for (int u = 0; u < 64; ++u) acc += sn[i][cb+u]*w[u];
    }
    qtbuf[((size_t)b*8 + i)*256 + col] = SCALE_*acc;
}

// ---------------- per-iter: fused attn (unchanged, validated) ----------------
__global__ __launch_bounds__(512)
void attn_kernel(const unsigned short* __restrict__ XH, const float* __restrict__ qt,
                 const float* __restrict__ qb, float* __restrict__ Spart,
                 float* __restrict__ Upart){
    __shared__ __align__(16) unsigned short xs[2*16384];
    __shared__ __align__(16) unsigned short pst[16*72];
    __shared__ float swred[4][8];
    const int t = threadIdx.x, b = blockIdx.x, jb = blockIdx.y;
    const unsigned short* XB = XH + (size_t)(b*16 + jb)*65536;
    const int wv = t >> 6, l = t & 63;
    const int bi = l & 15, kg = l >> 4;
    const bool isQK = (wv < 4), isPV = (wv >= 4);

    bf16x8 bfrag[8];
    float qbl = 0.f;
    {
        const ushort8 zz = (ushort8){0,0,0,0,0,0,0,0};
        #pragma unroll
        for (int ks = 0; ks < 8; ++ks) bfrag[ks] = __builtin_bit_cast(bf16x8, zz);
        if (isQK && bi < 8){
            #pragma unroll
            for (int ks = 0; ks < 8; ++ks){
                const float* qp = qt + ((size_t)b*8 + bi)*256 + ks*32 + kg*8;
                float4 qa = *(const float4*)qp;
                float4 qc = *(const float4*)(qp + 4);
                ushort8 pk;
                pk[0]=f2bf(qa.x); pk[1]=f2bf(qa.y); pk[2]=f2bf(qa.z); pk[3]=f2bf(qa.w);
                pk[4]=f2bf(qc.x); pk[5]=f2bf(qc.y); pk[6]=f2bf(qc.z); pk[7]=f2bf(qc.w);
                bfrag[ks] = __builtin_bit_cast(bf16x8, pk);
            }
            qbl = qb[(size_t)b*8 + bi];
        }
    }
    ushort8 SbA[4], SbB[4];
    const int strow[4] = { (l >> 2), 16 + (l >> 2), 32 + (l >> 2), 48 + (l >> 2) };
    f32x4 acc[4];
    #pragma unroll
    for (int n = 0; n < 4; ++n) acc[n] = (f32x4){0.f,0.f,0.f,0.f};
    const int pv_lo = bi & 7;
    const int pv_sl = (bi >> 3) ^ (kg << 1);
    float s8loc = 0.f;

#define STG_LOAD(Sb, ch) { \
    const unsigned short* gp = XB + (size_t)wv*8192 + (ch)*2048 + l*8; \
    _Pragma("unroll") for (int u = 0; u < 4; ++u) Sb[u] = *(const ushort8*)(gp + u*512); }
#define STG_WRITE(Sb, ch) { \
    unsigned short* xw = &xs[((ch)&1)*16384]; \
    _Pragma("unroll") for (int u = 0; u < 4; ++u){ \
        int rr = strow[u]; \
        int o = (wv*4 + (l & 3)) ^ ((rr & 7) ^ (((rr >> 3) & 3) << 1)); \
        *(ushort8*)&xw[rr*256 + o*8] = Sb[u]; } }
#define BARR() { asm volatile("s_waitcnt lgkmcnt(0)" ::: "memory"); __builtin_amdgcn_s_barrier(); }

#define QK_PHASE(p) if (isQK){ \
    const int cur = ((p)&1)*16384; \
    f32x4 qacc = (f32x4){0.f,0.f,0.f,0.f}; \
    const int rowL = wv*16 + bi; \
    const int swrow = (rowL & 7) ^ (((rowL >> 3) & 3) << 1); \
    const unsigned short* xrow = &xs[cur + rowL*256]; \
    _Pragma("unroll") for (int ks = 0; ks < 8; ++ks){ \
        int chn = (ks*4 + kg) ^ swrow; \
        bf16x8 af = *(const bf16x8*)&xrow[chn*8]; \
        qacc = __builtin_amdgcn_mfma_f32_16x16x32_bf16(af, bfrag[ks], qacc, 0, 0, 0); } \
    ushort4v p4; \
    _Pragma("unroll") for (int rr = 0; rr < 4; ++rr){ \
        float d = qacc[rr] + qbl; \
        float mx = d; \
        mx = fmaxf(mx, __shfl_xor(mx, 1)); \
        mx = fmaxf(mx, __shfl_xor(mx, 2)); \
        mx = fmaxf(mx, __shfl_xor(mx, 4)); \
        float e = __expf(d - mx); \
        float se = e; \
        se += __shfl_xor(se, 1); \
        se += __shfl_xor(se, 2); \
        se += __shfl_xor(se, 4); \
        float pv = e/se + EPS_; \
        p4[rr] = f2bf(pv); \
        if (bi < 8) s8loc += pv; } \
    if (bi < 8) *(ushort4v*)&pst[bi*72 + wv*16 + kg*4] = p4; }

#define PV_PHASE(p) if (isPV){ \
    const int cur = ((p)&1)*16384; \
    _Pragma("unroll") for (int kh = 0; kh < 2; ++kh){ \
        ushort8 pa = *(const ushort8*)&pst[bi*72 + kh*32 + kg*8]; \
        _Pragma("unroll") for (int n = 0; n < 4; ++n){ \
            const int ct2 = ((wv - 4)*4 + n) << 1; \
            ushort8 xv; \
            _Pragma("unroll") for (int e = 0; e < 8; ++e){ \
                int slot = ct2 ^ pv_sl ^ e; \
                xv[e] = xs[cur + kh*8192 + kg*2048 + e*256 + (slot << 3) + pv_lo]; } \
            acc[n] = __builtin_amdgcn_mfma_f32_16x16x32_bf16( \
                __builtin_bit_cast(bf16x8, pa), __builtin_bit_cast(bf16x8, xv), acc[n], 0, 0, 0); } } }

    STG_LOAD(SbA, 0); STG_WRITE(SbA, 0);
    STG_LOAD(SbB, 1);
    BARR();

    STG_LOAD(SbA, 2);
    QK_PHASE(0)
    BARR();
    PV_PHASE(0)
    STG_WRITE(SbB, 1);
    BARR();
    STG_LOAD(SbB, 3);
    QK_PHASE(1)
    BARR();
    PV_PHASE(1)
    STG_WRITE(SbA, 2);
    BARR();
    QK_PHASE(2)
    BARR();
    PV_PHASE(2)
    STG_WRITE(SbB, 3);
    BARR();
    QK_PHASE(3)
    BARR();
    PV_PHASE(3)

    if (isQK){
        float s = s8loc;
        s += __shfl_xor(s, 16);
        s += __shfl_xor(s, 32);
        if (l < 8) swred[wv][l] = s;
    }
    BARR();
    if (t < 8)
        Spart[((size_t)(b*16 + jb))*8 + t] =
            swred[0][t] + swred[1][t] + swred[2][t] + swred[3][t];
    if (isPV && kg < 2){
        #pragma unroll
        for (int n = 0; n < 4; ++n){
            const int ct = (wv - 4)*4 + n;
            #pragma unroll
            for (int r2 = 0; r2 < 4; ++r2){
                int i = kg*4 + r2;
                Upart[(((size_t)(b*16 + jb))*8 + i)*256 + ct*16 + bi] = acc[n][r2];
            }
        }
    }
#undef STG_LOAD
#undef STG_WRITE
#undef BARR
#undef QK_PHASE
#undef PV_PHASE
}

// ---------------- per-iter: slotu1 = Upart reduce + Wv GEMM + GRU n-slice  (grid (B,4), 512) ----------------
__global__ __launch_bounds__(512, 1)
void slotu1_kernel(const float* __restrict__ slots, const float* __restrict__ Spart,
                   const float* __restrict__ Upart, const float* __restrict__ Wv,
                   const float* __restrict__ bv, const float* __restrict__ W_ih,
                   const float* __restrict__ b_ih, const float* __restrict__ W_hh,
                   const float* __restrict__ b_hh, float* __restrict__ slots2){
    __shared__ float us[8][260], sp[8][260], upd[8][260];
    const int t = threadIdx.x, b = blockIdx.x, ng = blockIdx.y;
    const int i = t >> 6, l = t & 63;
    {
        float a0 = 0.f, a1 = 0.f, a2 = 0.f, a3 = 0.f, S = 0.f;
        #pragma unroll
        for (int jbl = 0; jbl < 16; ++jbl){
            float4 u4 = *(const float4*)(Upart + (((size_t)(b*16 + jbl))*8 + i)*256 + l*4);
            a0 += u4.x; a1 += u4.y; a2 += u4.z; a3 += u4.w;
            S += Spart[((size_t)(b*16 + jbl))*8 + i];
        }
        float invS = 1.f / S;
        us[i][l*4+0] = a0*invS; us[i][l*4+1] = a1*invS;
        us[i][l*4+2] = a2*invS; us[i][l*4+3] = a3*invS;
        float4 s4 = *(const float4*)(slots + ((size_t)b*8 + i)*256 + l*4);
        sp[i][l*4+0] = s4.x; sp[i][l*4+1] = s4.y; sp[i][l*4+2] = s4.z; sp[i][l*4+3] = s4.w;
    }
    __syncthreads();
    {
        const int c4 = l*4;
        float4 acc = *(const float4*)(bv + c4);
        #pragma unroll
        for (int cb = 0; cb < 256; cb += 16){
            float4 w4[16];
            #pragma unroll
            for (int u = 0; u < 16; ++u)
                w4[u] = *(const float4*)(Wv + (size_t)(cb+u)*256 + c4);
            #pragma unroll
            for (int u = 0; u < 16; ++u){
                float uv = us[i][cb+u];
                acc.x += uv*w4[u].x; acc.y += uv*w4[u].y;
                acc.z += uv*w4[u].z; acc.w += uv*w4[u].w;
            }
        }
        *(float4*)&upd[i][c4] = acc;
    }
    __syncthreads();
    {
        const int n = ng*64 + l;
        float xr = b_ih[n], xz = b_ih[256+n], xn = b_ih[512+n];
        float hr = b_hh[n], hz = b_hh[256+n], hn = b_hh[512+n];
        #pragma unroll 2
        for (int cb = 0; cb < 256; cb += 8){
            float wi0[8], wi1[8], wi2[8], wh0[8], wh1[8], wh2[8];
            #pragma unroll
            for (int u = 0; u < 8; ++u){
                const float* wi = W_ih + (size_t)(cb+u)*768 + n;
                const float* wh = W_hh + (size_t)(cb+u)*768 + n;
                wi0[u] = wi[0]; wi1[u] = wi[256]; wi2[u] = wi[512];
                wh0[u] = wh[0]; wh1[u] = wh[256]; wh2[u] = wh[512];
            }
            #pragma unroll
            for (int u = 0; u < 8; ++u){
                float uv = upd[i][cb+u], sv = sp[i][cb+u];
                xr += uv*wi0[u]; xz += uv*wi1[u]; xn += uv*wi2[u];
                hr += sv*wh0[u]; hz += sv*wh1[u]; hn += sv*wh2[u];
            }
        }
        float rv = 1.f/(1.f + __expf(-(xr + hr)));
        float zv = 1.f/(1.f + __expf(-(xz + hz)));
        float nn = tanhf(xn + rv*hn);
        slots2[((size_t)b*8 + i)*256 + n] = (1.f - zv)*nn + zv*sp[i][n];
    }
}

// ---------------- per-iter: slotu2 = LN_ff + FFN1 + FFN2 n-slice  (grid (B,4), 512) ----------------
__global__ __launch_bounds__(512, 1)
void slotu2_kernel(const float* __restrict__ slots2, const float* __restrict__ gf,
                   const float* __restrict__ bf, const float* __restrict__ W1,
                   const float* __restrict__ b1, const float* __restrict__ W2,
                   const float* __restrict__ b2, float* __restrict__ slots,
                   float* __restrict__ dout){
    __shared__ float s0[8][260], pre[8][260], hb[8][260];
    const int t = threadIdx.x, b = blockIdx.x, ng = blockIdx.y;
    const int i = t >> 6, l = t & 63;
    {
        float4 v4 = *(const float4*)(slots2 + ((size_t)b*8 + i)*256 + l*4);
        float sum = v4.x + v4.y + v4.z + v4.w;
        float sq  = v4.x*v4.x + v4.y*v4.y + v4.z*v4.z + v4.w*v4.w;
        #pragma unroll
        for (int m = 1; m < 64; m <<= 1){ sum += __shfl_xor(sum, m); sq += __shfl_xor(sq, m); }
        float mean = sum * (1.f/256.f);
        float rstd = rsqrtf(sq * (1.f/256.f) - mean*mean + 1e-5f);
        float4 g4 = *(const float4*)(gf + l*4);
        float4 b4 = *(const float4*)(bf + l*4);
        s0[i][l*4+0] = v4.x; s0[i][l*4+1] = v4.y; s0[i][l*4+2] = v4.z; s0[i][l*4+3] = v4.w;
        pre[i][l*4+0] = (v4.x - mean)*rstd*g4.x + b4.x;
        pre[i][l*4+1] = (v4.y - mean)*rstd*g4.y + b4.y;
        pre[i][l*4+2] = (v4.z - mean)*rstd*g4.z + b4.z;
        pre[i][l*4+3] = (v4.w - mean)*rstd*g4.w + b4.w;
    }
    __syncthreads();
    {
        const int h4 = l*4;
        float4 acc = *(const float4*)(b1 + h4);
        #pragma unroll
        for (int cb = 0; cb < 256; cb += 16){
            float4 w4[16];
            #pragma unroll
            for (int u = 0; u < 16; ++u)
                w4[u] = *(const float4*)(W1 + (size_t)(cb+u)*256 + h4);
            #pragma unroll
            for (int u = 0; u < 16; ++u){
                float pv = pre[i][cb+u];
                acc.x += pv*w4[u].x; acc.y += pv*w4[u].y;
                acc.z += pv*w4[u].z; acc.w += pv*w4[u].w;
            }
        }
        hb[i][h4+0] = fmaxf(acc.x, 0.f); hb[i][h4+1] = fmaxf(acc.y, 0.f);
        hb[i][h4+2] = fmaxf(acc.z, 0.f); hb[i][h4+3] = fmaxf(acc.w, 0.f);
    }
    __syncthreads();
    {
        const int n = ng*64 + l;
        float acc = b2[n];
        #pragma unroll
        for (int mb = 0; mb < 256; mb += 64){
            float w[64];
            #pragma unroll
            for (int u = 0; u < 64; ++u) w[u] = W2[(size_t)(mb+u)*256 + n];
            #pragma unroll
            for (int u = 0; u < 64; ++u) acc += hb[i][mb+u]*w[u];
        }
        float val = s0[i][n] + acc;
        size_t off = ((size_t)b*8 + i)*256 + n;
        slots[off] = val;
        dout[off]  = val;
    }
}

extern "C" void kernel_launch(void* const* d_in, const int* in_sizes, int n_in,
                              void* d_out, int out_size, void* d_ws, size_t ws_size,
                              hipStream_t stream){
    const float* inputs = (const float*)d_in[0];
    const float* noise  = (const float*)d_in[1];
    const float* mu     = (const float*)d_in[2];
    const float* lsig   = (const float*)d_in[3];
    const float* g_in   = (const float*)d_in[4];
    const float* b_in   = (const float*)d_in[5];
    const float* g_s    = (const float*)d_in[6];
    const float* b_s    = (const float*)d_in[7];
    const float* g_ff   = (const float*)d_in[8];
    const float* b_ff   = (const float*)d_in[9];
    const float* Wq     = (const float*)d_in[10];
    const float* bq     = (const float*)d_in[11];
    const float* Wk     = (const float*)d_in[12];
    const float* bk     = (const float*)d_in[13];
    const float* Wv     = (const float*)d_in[14];
    const float* bv     = (const float*)d_in[15];
    const float* W_ih   = (const float*)d_in[16];
    const float* b_ih   = (const float*)d_in[17];
    const float* W_hh   = (const float*)d_in[18];
    const float* b_hh   = (const float*)d_in[19];
    const float* W1     = (const float*)d_in[20];
    const float* b1     = (const float*)d_in[21];
    const float* W2     = (const float*)d_in[22];
    const float* b2     = (const float*)d_in[23];

    char* ws = (char*)d_ws;
    unsigned short* XH  = (unsigned short*)(ws);               // 128 MB
    float* Upart        = (float*)(ws + ((size_t)128 << 20));  // 8 MB
    float* Spart        = (float*)(ws + ((size_t)136 << 20));  // 8 KB
    float* qtbuf        = (float*)(ws + ((size_t)137 << 20));  // 512 KB
    float* qbb          = (float*)(ws + ((size_t)138 << 20));  // 2 KB
    float* slots        = (float*)(ws + ((size_t)139 << 20));  // 512 KB
    float* slots2       = (float*)(ws + ((size_t)140 << 20));  // 512 KB
    float* WqkT         = (float*)(ws + ((size_t)141 << 20));  // 256 KB
    float* bqt          = (float*)(ws + ((size_t)142 << 20));  // 1 KB
    float* wqb          = (float*)(ws + ((size_t)143 << 20));  // 1 KB
    float* bqkv         = (float*)(ws + ((size_t)144 << 20));  // 4 B

    prep1_kernel<<<512, 256, 0, stream>>>(mu, lsig, noise, slots);
    prep2_kernel<<<256, 256, 0, stream>>>(Wq, Wk, bq, bk, WqkT, bqt, wqb, bqkv);
    ln_kernel<<<M_/32, 256, 0, stream>>>(inputs, g_in, b_in, XH);
    for (int it = 0; it < ITERS_; ++it){
        slotq_kernel<<<dim3(B_, 4), 512, 0, stream>>>(slots, WqkT, bqt, wqb, bqkv,
                                                      g_s, b_s, qtbuf, qbb);
        attn_kernel<<<dim3(B_, 16), 512, 0, stream>>>(XH, qtbuf, qbb, Spart, Upart);
        slotu1_kernel<<<dim3(B_, 4), 512, 0, stream>>>(slots, Spart, Upart, Wv, bv,
                                                       W_ih, b_ih, W_hh, b_hh, slots2);
        slotu2_kernel<<<dim3(B_, 4), 512, 0, stream>>>(slots2, g_ff, b_ff, W1, b1, W2, b2,
                                                       slots, (float*)d_out);
    }
}